// Round 3
// baseline (635.236 us; speedup 1.0000x reference)
//
#include <hip/hip_runtime.h>
#include <stdint.h>

// ---------- bf16 helpers (storage = unsigned short) ----------
__device__ __forceinline__ float b2f(unsigned short u) {
    union { uint32_t i; float f; } v; v.i = ((uint32_t)u) << 16; return v.f;
}
__device__ __forceinline__ unsigned short f2b(float f) {
    union { float f; uint32_t i; } v; v.f = f;
    uint32_t r = v.i + 0x7fffu + ((v.i >> 16) & 1u);   // RNE
    return (unsigned short)(r >> 16);
}

typedef __bf16 bf16x8 __attribute__((ext_vector_type(8)));
typedef float  f32x4  __attribute__((ext_vector_type(4)));

// ---------- on-device dtype probe ----------
// bf16 N(0,1) data: every uint16 exponent field in ~[118,130].
// fp32 N(0,1) data read as uint16: half the elements are mantissa garbage with
// ~uniform exponent fields -> count in-range ~ 64+10 of 128. Threshold 110.
__device__ __forceinline__ bool detect_bf16(const unsigned short* x) {
    int cnt = 0;
#pragma unroll 8
    for (int i = 0; i < 128; ++i) {
        int e = (x[i] >> 7) & 0xff;
        cnt += (e >= 100 && e <= 140) ? 1 : 0;
    }
    return cnt >= 110;
}

__device__ __forceinline__ float load_elem(const void* p, int idx, bool isbf) {
    return isbf ? b2f(((const unsigned short*)p)[idx]) : ((const float*)p)[idx];
}

// ---------------------------------------------------------------------------
// build_T: T[rm=(r1*16+n2)*16+m2][n3][m3] = sum_r2 c1[rm][r2]*c2[(r2*N3+n3)*M3+m3]
// ---------------------------------------------------------------------------
template<int N3, int M3>
__global__ void build_T(const void* __restrict__ c1,
                        const void* __restrict__ c2,
                        float* __restrict__ T,
                        const unsigned short* __restrict__ xdet) {
    const bool isbf = detect_bf16(xdet);
    int e = blockIdx.x * 256 + threadIdx.x;
    int m3 = e % M3;
    int t  = e / M3;
    int n3 = t % N3;
    int rm = t / N3;
    float s = 0.f;
#pragma unroll
    for (int r2 = 0; r2 < 16; ++r2)
        s += load_elem(c1, rm * 16 + r2, isbf) *
             load_elem(c2, (r2 * N3 + n3) * M3 + m3, isbf);
    T[e] = s;
}

// ---------------------------------------------------------------------------
// build_W: W[M][K] bf16 = sum_r1 c0[(n1*M1+m1)*16+r1] * T[((r1*16+n2)*16+m2)...]
// M=(m1,m2,m3) row-major; K=(n1,n2,n3) row-major.
// ---------------------------------------------------------------------------
template<int N1, int N2, int N3, int M1, int M2, int M3>
__global__ void build_W(const void* __restrict__ c0,
                        const float* __restrict__ T,
                        unsigned short* __restrict__ W,
                        const unsigned short* __restrict__ xdet) {
    const bool isbf = detect_bf16(xdet);
    constexpr int K = N1 * N2 * N3;
    int e = blockIdx.x * 256 + threadIdx.x;
    int k = e % K;
    int M = e / K;
    int n3 = k % N3;
    int n2 = (k / N3) % N2;
    int n1 = k / (N3 * N2);
    int m3 = M % M3;
    int m2 = (M / M3) % M2;
    int m1 = M / (M3 * M2);
    float s = 0.f;
#pragma unroll
    for (int r1 = 0; r1 < 16; ++r1)
        s += load_elem(c0, (n1 * M1 + m1) * 16 + r1, isbf) *
             T[(((r1 * 16 + n2) * 16 + m2) * N3 + n3) * M3 + m3];
    W[e] = f2b(s);
}

// ---------------------------------------------------------------------------
// GEMM: C[M][N] = A[M][K] * Bt[N][K]^T + bias[N], optional exact GELU.
// ROLE 1: A = dataset dtype (x), C = bf16 (internal h).
// ROLE 2: A = bf16 (internal h), C = dataset dtype (out).
// bias is always dataset dtype. B is always internal bf16.
// ---------------------------------------------------------------------------
template<int KTOT, bool DO_GELU, int ROLE>
__global__ __launch_bounds__(256)
void gemm_bias_act(const void* __restrict__ Av,
                   const unsigned short* __restrict__ Bt,
                   const void* __restrict__ biasv,
                   void* __restrict__ Cv,
                   int Ncols,
                   const unsigned short* __restrict__ xdet) {
    const bool det = detect_bf16(xdet);       // true => dataset is bf16
    const bool a32 = (ROLE == 1) && !det;     // A loads are fp32
    const bool c32 = (ROLE == 2) && !det;     // C stores are fp32

    constexpr int BK = 64;
    __shared__ unsigned short As[128 * BK];
    __shared__ unsigned short Bs[128 * BK];

    const int tid  = threadIdx.x;
    const int lane = tid & 63;
    const int wave = tid >> 6;
    const int rowBase = blockIdx.y * 128;
    const int colBase = blockIdx.x * 128;

    const int waveM = (wave >> 1) * 64;
    const int waveN = (wave & 1) * 64;

    f32x4 acc[4][4] = {};

    const int ldRow = lane >> 3;          // 0..7
    const int ldCol = (lane & 7) * 8;     // element offset (16B bf16 granules)
    const int mrow  = lane & 15;
    const int kq    = (lane >> 4) * 8;

    for (int k0 = 0; k0 < KTOT; k0 += BK) {
#pragma unroll
        for (int it = 0; it < 4; ++it) {
            const int c = wave * 4 + it;                   // chunk 0..15
            const size_t aoff = (size_t)(rowBase + c * 8 + ldRow) * KTOT + k0 + ldCol;
            if (a32) {
                const float* ga = (const float*)Av + aoff;
                float4 f0 = *(const float4*)ga;
                float4 f1 = *(const float4*)(ga + 4);
                int4 p;
                p.x = (uint32_t)f2b(f0.x) | ((uint32_t)f2b(f0.y) << 16);
                p.y = (uint32_t)f2b(f0.z) | ((uint32_t)f2b(f0.w) << 16);
                p.z = (uint32_t)f2b(f1.x) | ((uint32_t)f2b(f1.y) << 16);
                p.w = (uint32_t)f2b(f1.z) | ((uint32_t)f2b(f1.w) << 16);
                *(int4*)&As[c * 512 + lane * 8] = p;
            } else {
                *(int4*)&As[c * 512 + lane * 8] =
                    *(const int4*)((const unsigned short*)Av + aoff);
            }
            const unsigned short* gb = Bt + (size_t)(colBase + c * 8 + ldRow) * KTOT + k0 + ldCol;
            *(int4*)&Bs[c * 512 + lane * 8] = *(const int4*)gb;
        }
        __syncthreads();

#pragma unroll
        for (int ks = 0; ks < 2; ++ks) {
            bf16x8 a_f[4], b_f[4];
#pragma unroll
            for (int i = 0; i < 4; ++i)
                a_f[i] = *(const bf16x8*)&As[(waveM + i * 16 + mrow) * BK + ks * 32 + kq];
#pragma unroll
            for (int j = 0; j < 4; ++j)
                b_f[j] = *(const bf16x8*)&Bs[(waveN + j * 16 + mrow) * BK + ks * 32 + kq];
#pragma unroll
            for (int i = 0; i < 4; ++i)
#pragma unroll
                for (int j = 0; j < 4; ++j)
                    acc[i][j] = __builtin_amdgcn_mfma_f32_16x16x32_bf16(
                        a_f[i], b_f[j], acc[i][j], 0, 0, 0);
        }
        __syncthreads();
    }

    // Epilogue: C/D layout col(n)=lane&15, row(m)=(lane>>4)*4+reg
    const int cRow = (lane >> 4) * 4;
    const int cCol = lane & 15;
#pragma unroll
    for (int i = 0; i < 4; ++i) {
#pragma unroll
        for (int j = 0; j < 4; ++j) {
            const int col = colBase + waveN + j * 16 + cCol;
            const float bv = det ? b2f(((const unsigned short*)biasv)[col])
                                 : ((const float*)biasv)[col];
#pragma unroll
            for (int r = 0; r < 4; ++r) {
                const int row = rowBase + waveM + i * 16 + cRow + r;
                float z = acc[i][j][r] + bv;
                if (DO_GELU)
                    z = 0.5f * z * (1.f + erff(z * 0.70710678118654752f));
                const size_t off = (size_t)row * Ncols + col;
                if (c32) ((float*)Cv)[off] = z;
                else     ((unsigned short*)Cv)[off] = f2b(z);
            }
        }
    }
}

// ---------------------------------------------------------------------------
extern "C" void kernel_launch(void* const* d_in, const int* in_sizes, int n_in,
                              void* d_out, int out_size, void* d_ws, size_t ws_size,
                              hipStream_t stream) {
    const void* x      = d_in[0];                                  // [4096,1024]
    const void* fc1_c0 = d_in[1];  const void* fc1_c1 = d_in[2];
    const void* fc1_c2 = d_in[3];  const void* fc1_b  = d_in[4];
    const void* fc2_c0 = d_in[5];  const void* fc2_c1 = d_in[6];
    const void* fc2_c2 = d_in[7];  const void* fc2_b  = d_in[8];
    const unsigned short* xdet = (const unsigned short*)d_in[0];

    // Workspace (42 MB peak):
    //   [0,8M)   W   bf16 — holds W1t [4096][1024], later overwritten by W2t [1024][4096]
    //   [8,10M)  T   f32 scratch (re-used per layer)
    //   [10,42M) h   bf16 [4096][4096]
    char* ws = (char*)d_ws;
    unsigned short* W = (unsigned short*)(ws);
    float*          T = (float*)(ws + (8u << 20));
    unsigned short* h = (unsigned short*)(ws + (10u << 20));

    // ---- layer 1: in (8,16,8) -> out (16,16,16)
    build_T<8, 16><<<2048, 256, 0, stream>>>(fc1_c1, fc1_c2, T, xdet);
    build_W<8, 16, 8, 16, 16, 16><<<16384, 256, 0, stream>>>(fc1_c0, T, W, xdet);
    // GEMM1: h = gelu(x @ W1^T + b1)   [4096 x 4096], K=1024
    gemm_bias_act<1024, true, 1><<<dim3(32, 32), 256, 0, stream>>>(x, W, fc1_b, h, 4096, xdet);

    // ---- layer 2: in (16,16,16) -> out (8,16,8)  (W slot reused after GEMM1)
    build_T<16, 8><<<2048, 256, 0, stream>>>(fc2_c1, fc2_c2, T, xdet);
    build_W<16, 16, 16, 8, 16, 8><<<16384, 256, 0, stream>>>(fc2_c0, T, W, xdet);
    // GEMM2: out = h @ W2^T + b2       [4096 x 1024], K=4096
    gemm_bias_act<4096, false, 2><<<dim3(8, 32), 256, 0, stream>>>(h, W, fc2_b, d_out, 1024, xdet);
}

// Round 4
// 489.005 us; speedup vs baseline: 1.2990x; 1.2990x over previous
//
#include <hip/hip_runtime.h>
#include <stdint.h>

// ---------- bf16 helpers (storage = unsigned short) ----------
__device__ __forceinline__ float b2f(unsigned short u) {
    union { uint32_t i; float f; } v; v.i = ((uint32_t)u) << 16; return v.f;
}
__device__ __forceinline__ unsigned short f2b(float f) {
    union { float f; uint32_t i; } v; v.f = f;
    uint32_t r = v.i + 0x7fffu + ((v.i >> 16) & 1u);   // RNE
    return (unsigned short)(r >> 16);
}

typedef __bf16 bf16x8 __attribute__((ext_vector_type(8)));
typedef float  f32x4  __attribute__((ext_vector_type(4)));

// ---------- 16B/lane async stage: global -> LDS ----------
// LDS side must be wave-uniform base + lane*16 (it is: c is wave-uniform,
// lane*16 contiguous). Global side is a normal per-lane vector address.
__device__ __forceinline__ void stage16(const unsigned short* g, unsigned short* l) {
    __builtin_amdgcn_global_load_lds(
        (const __attribute__((address_space(1))) void*)g,
        (__attribute__((address_space(3))) void*)l, 16, 0, 0);
}

// ---------------------------------------------------------------------------
// build_T: T[rm=(r1*16+n2)*16+m2][n3][m3] = sum_r2 c1[rm][r2]*c2[(r2*N3+n3)*M3+m3]
// c1: fp32 [4096][16], c2: fp32 [16][N3*M3]. 524288 output elems.
// ---------------------------------------------------------------------------
template<int N3, int M3>
__global__ void build_T(const float* __restrict__ c1,
                        const float* __restrict__ c2,
                        float* __restrict__ T) {
    int e = blockIdx.x * 256 + threadIdx.x;
    int m3 = e % M3;
    int t  = e / M3;
    int n3 = t % N3;
    int rm = t / N3;
    float s = 0.f;
#pragma unroll
    for (int r2 = 0; r2 < 16; ++r2)
        s += c1[rm * 16 + r2] * c2[(r2 * N3 + n3) * M3 + m3];
    T[e] = s;
}

// ---------------------------------------------------------------------------
// build_W: W[M][K] bf16 = sum_r1 c0[(n1*M1+m1)*16+r1] * T[((r1*16+n2)*16+m2)*N3*M3 + n3*M3 + m3]
// M=(m1,m2,m3) row-major; K=(n1,n2,n3) row-major. c0: fp32.
// ---------------------------------------------------------------------------
template<int N1, int N2, int N3, int M1, int M2, int M3>
__global__ void build_W(const float* __restrict__ c0,
                        const float* __restrict__ T,
                        unsigned short* __restrict__ W) {
    constexpr int K = N1 * N2 * N3;
    int e = blockIdx.x * 256 + threadIdx.x;
    int k = e % K;
    int M = e / K;
    int n3 = k % N3;
    int n2 = (k / N3) % N2;
    int n1 = k / (N3 * N2);
    int m3 = M % M3;
    int m2 = (M / M3) % M2;
    int m1 = M / (M3 * M2);
    float s = 0.f;
#pragma unroll
    for (int r1 = 0; r1 < 16; ++r1)
        s += c0[(n1 * M1 + m1) * 16 + r1] *
             T[(((r1 * 16 + n2) * 16 + m2) * N3 + n3) * M3 + m3];
    W[e] = f2b(s);
}

// ---------------------------------------------------------------------------
// GEMM: C[M][N] = A[M][K] * Bt[N][K]^T + bias[N] (fp32), optional exact GELU.
// 128x128 tile, BK=64, 4 waves, each wave 64x64 via 4x4 of 16x16x32 bf16 MFMA.
// A_F32: A is fp32 -> register repack to bf16 during staging.
//        else A is bf16 -> global_load_lds width-16.
// C_F32: store fp32; else store bf16.
// ---------------------------------------------------------------------------
template<int KTOT, bool DO_GELU, bool A_F32, bool C_F32>
__global__ __launch_bounds__(256)
void gemm_bias_act(const void* __restrict__ Av,
                   const unsigned short* __restrict__ Bt,
                   const float* __restrict__ bias,
                   void* __restrict__ Cv,
                   int Ncols) {
    constexpr int BK = 64;
    __shared__ unsigned short As[128 * BK];
    __shared__ unsigned short Bs[128 * BK];

    const int tid  = threadIdx.x;
    const int lane = tid & 63;
    const int wave = tid >> 6;
    const int rowBase = blockIdx.y * 128;
    const int colBase = blockIdx.x * 128;

    const int waveM = (wave >> 1) * 64;
    const int waveN = (wave & 1) * 64;

    f32x4 acc[4][4] = {};

    const int ldRow = lane >> 3;          // 0..7
    const int ldCol = (lane & 7) * 8;     // element offset (8 elems/lane)
    const int mrow  = lane & 15;
    const int kq    = (lane >> 4) * 8;

    for (int k0 = 0; k0 < KTOT; k0 += BK) {
#pragma unroll
        for (int it = 0; it < 4; ++it) {
            const int c = wave * 4 + it;                   // chunk 0..15
            const size_t aoff = (size_t)(rowBase + c * 8 + ldRow) * KTOT + k0 + ldCol;
            if (A_F32) {
                const float* ga = (const float*)Av + aoff;
                float4 f0 = *(const float4*)ga;
                float4 f1 = *(const float4*)(ga + 4);
                int4 p;
                p.x = (uint32_t)f2b(f0.x) | ((uint32_t)f2b(f0.y) << 16);
                p.y = (uint32_t)f2b(f0.z) | ((uint32_t)f2b(f0.w) << 16);
                p.z = (uint32_t)f2b(f1.x) | ((uint32_t)f2b(f1.y) << 16);
                p.w = (uint32_t)f2b(f1.z) | ((uint32_t)f2b(f1.w) << 16);
                *(int4*)&As[c * 512 + lane * 8] = p;
            } else {
                stage16((const unsigned short*)Av + aoff, &As[c * 512 + lane * 8]);
            }
            stage16(Bt + (size_t)(colBase + c * 8 + ldRow) * KTOT + k0 + ldCol,
                    &Bs[c * 512 + lane * 8]);
        }
        __syncthreads();

#pragma unroll
        for (int ks = 0; ks < 2; ++ks) {
            bf16x8 a_f[4], b_f[4];
#pragma unroll
            for (int i = 0; i < 4; ++i)
                a_f[i] = *(const bf16x8*)&As[(waveM + i * 16 + mrow) * BK + ks * 32 + kq];
#pragma unroll
            for (int j = 0; j < 4; ++j)
                b_f[j] = *(const bf16x8*)&Bs[(waveN + j * 16 + mrow) * BK + ks * 32 + kq];
#pragma unroll
            for (int i = 0; i < 4; ++i)
#pragma unroll
                for (int j = 0; j < 4; ++j)
                    acc[i][j] = __builtin_amdgcn_mfma_f32_16x16x32_bf16(
                        a_f[i], b_f[j], acc[i][j], 0, 0, 0);
        }
        __syncthreads();
    }

    // Epilogue: C/D layout col(n)=lane&15, row(m)=(lane>>4)*4+reg
    const int cRow = (lane >> 4) * 4;
    const int cCol = lane & 15;
#pragma unroll
    for (int i = 0; i < 4; ++i) {
#pragma unroll
        for (int j = 0; j < 4; ++j) {
            const int col = colBase + waveN + j * 16 + cCol;
            const float bv = bias[col];
#pragma unroll
            for (int r = 0; r < 4; ++r) {
                const int row = rowBase + waveM + i * 16 + cRow + r;
                float z = acc[i][j][r] + bv;
                if (DO_GELU)
                    z = 0.5f * z * (1.f + erff(z * 0.70710678118654752f));
                const size_t off = (size_t)row * Ncols + col;
                if (C_F32) ((float*)Cv)[off] = z;
                else       ((unsigned short*)Cv)[off] = f2b(z);
            }
        }
    }
}

// ---------------------------------------------------------------------------
extern "C" void kernel_launch(void* const* d_in, const int* in_sizes, int n_in,
                              void* d_out, int out_size, void* d_ws, size_t ws_size,
                              hipStream_t stream) {
    const float* x      = (const float*)d_in[0];   // [4096,1024] fp32
    const float* fc1_c0 = (const float*)d_in[1];   // [1,8,16,16]
    const float* fc1_c1 = (const float*)d_in[2];   // [16,16,16,16]
    const float* fc1_c2 = (const float*)d_in[3];   // [16,8,16,1]
    const float* fc1_b  = (const float*)d_in[4];   // [4096]
    const float* fc2_c0 = (const float*)d_in[5];   // [1,16,8,16]
    const float* fc2_c1 = (const float*)d_in[6];   // [16,16,16,16]
    const float* fc2_c2 = (const float*)d_in[7];   // [16,16,8,1]
    const float* fc2_b  = (const float*)d_in[8];   // [1024]

    // Workspace (42 MB peak):
    //   [0,8M)   W   bf16 — W1t [4096][1024], later overwritten by W2t [1024][4096]
    //   [8,10M)  T   f32 scratch (re-used per layer)
    //   [10,42M) h   bf16 [4096][4096]
    char* ws = (char*)d_ws;
    unsigned short* W = (unsigned short*)(ws);
    float*          T = (float*)(ws + (8u << 20));
    unsigned short* h = (unsigned short*)(ws + (10u << 20));

    // ---- layer 1: in (8,16,8) -> out (16,16,16)
    build_T<8, 16><<<2048, 256, 0, stream>>>(fc1_c1, fc1_c2, T);
    build_W<8, 16, 8, 16, 16, 16><<<16384, 256, 0, stream>>>(fc1_c0, T, W);
    // GEMM1: h = gelu(x @ W1^T + b1)   [4096 x 4096], K=1024, A fp32, C bf16
    gemm_bias_act<1024, true, true, false>
        <<<dim3(32, 32), 256, 0, stream>>>(x, W, fc1_b, h, 4096);

    // ---- layer 2: in (16,16,16) -> out (8,16,8)
    build_T<16, 8><<<2048, 256, 0, stream>>>(fc2_c1, fc2_c2, T);
    build_W<16, 16, 16, 8, 16, 8><<<16384, 256, 0, stream>>>(fc2_c0, T, W);
    // GEMM2: out = h @ W2^T + b2       [4096 x 1024], K=4096, A bf16, C fp32
    gemm_bias_act<4096, false, false, true>
        <<<dim3(8, 32), 256, 0, stream>>>(h, W, fc2_b, d_out, 1024);
}

// Round 5
// 279.543 us; speedup vs baseline: 2.2724x; 1.7493x over previous
//
#include <hip/hip_runtime.h>
#include <stdint.h>

// ---------- bf16 helpers (storage = unsigned short) ----------
__device__ __forceinline__ float b2f(unsigned short u) {
    union { uint32_t i; float f; } v; v.i = ((uint32_t)u) << 16; return v.f;
}
__device__ __forceinline__ unsigned short f2b(float f) {
    union { float f; uint32_t i; } v; v.f = f;
    uint32_t r = v.i + 0x7fffu + ((v.i >> 16) & 1u);   // RNE
    return (unsigned short)(r >> 16);
}

typedef __bf16 bf16x8 __attribute__((ext_vector_type(8)));
typedef float  f32x4  __attribute__((ext_vector_type(4)));

// ---------- 16B/lane async stage: global -> LDS ----------
__device__ __forceinline__ void stage16(const unsigned short* g, unsigned short* l) {
    __builtin_amdgcn_global_load_lds(
        (const __attribute__((address_space(1))) void*)g,
        (__attribute__((address_space(3))) void*)l, 16, 0, 0);
}

// ---------------------------------------------------------------------------
// build_T: T[rm=(r1*16+n2)*16+m2][n3][m3] = sum_r2 c1[rm][r2]*c2[(r2*N3+n3)*M3+m3]
// ---------------------------------------------------------------------------
template<int N3, int M3>
__global__ void build_T(const float* __restrict__ c1,
                        const float* __restrict__ c2,
                        float* __restrict__ T) {
    int e = blockIdx.x * 256 + threadIdx.x;
    int m3 = e % M3;
    int t  = e / M3;
    int n3 = t % N3;
    int rm = t / N3;
    float s = 0.f;
#pragma unroll
    for (int r2 = 0; r2 < 16; ++r2)
        s += c1[rm * 16 + r2] * c2[(r2 * N3 + n3) * M3 + m3];
    T[e] = s;
}

// ---------------------------------------------------------------------------
// build_W v2 — coalesced remap.
// Thread id t = (((n1*M1 + m1)*N2 + n2)*M2 + m2)*M3 + m3  (m3 fastest ->
// lane-contiguous T addresses). Each thread loops the full n3 range and
// writes N3 consecutive bf16 (vector store).
//   W[M][K], M=(m1,m2,m3) row-major, K=(n1,n2,n3) row-major:
//   W idx = ((m1*M2+m2)*M3+m3)*K + (n1*N2+n2)*N3 + n3
//   T idx = (((r1*16+n2)*16+m2)*N3 + n3)*M3 + m3
// ---------------------------------------------------------------------------
template<int N1, int N2, int N3, int M1, int M2, int M3>
__global__ __launch_bounds__(256)
void build_W(const float* __restrict__ c0,
             const float* __restrict__ T,
             unsigned short* __restrict__ W) {
    constexpr int K = N1 * N2 * N3;
    int t  = blockIdx.x * 256 + threadIdx.x;
    int m3 = t % M3;
    int m2 = (t / M3) % M2;
    int n2 = (t / (M3 * M2)) % N2;
    int m1 = (t / (M3 * M2 * N2)) % M1;
    int n1 =  t / (M3 * M2 * N2 * M1);

    // c0 row for (n1,m1): 16 consecutive fp32
    float c0r[16];
    const float4* c0p = (const float4*)(c0 + (n1 * M1 + m1) * 16);
#pragma unroll
    for (int i = 0; i < 4; ++i) ((float4*)c0r)[i] = c0p[i];

    float acc[N3] = {};
#pragma unroll
    for (int r1 = 0; r1 < 16; ++r1) {
        const float* Tp = T + (size_t)(((r1 * 16 + n2) * 16 + m2) * N3) * M3 + m3;
#pragma unroll
        for (int n3 = 0; n3 < N3; ++n3)
            acc[n3] += c0r[r1] * Tp[n3 * M3];
    }

    unsigned short ob[N3];
#pragma unroll
    for (int n3 = 0; n3 < N3; ++n3) ob[n3] = f2b(acc[n3]);

    unsigned short* dst = W + (size_t)((m1 * M2 + m2) * M3 + m3) * K
                            + (n1 * N2 + n2) * N3;
#pragma unroll
    for (int c = 0; c < N3 / 8; ++c)
        ((int4*)dst)[c] = ((const int4*)ob)[c];
}

// ---------------------------------------------------------------------------
// GEMM: C[M][N] = A[M][K] * Bt[N][K]^T + bias[N] (fp32), optional exact GELU.
// 128x128 tile, BK=64, 4 waves, 4x4 of 16x16x32 bf16 MFMA per wave.
// ---------------------------------------------------------------------------
template<int KTOT, bool DO_GELU, bool A_F32, bool C_F32>
__global__ __launch_bounds__(256)
void gemm_bias_act(const void* __restrict__ Av,
                   const unsigned short* __restrict__ Bt,
                   const float* __restrict__ bias,
                   void* __restrict__ Cv,
                   int Ncols) {
    constexpr int BK = 64;
    __shared__ unsigned short As[128 * BK];
    __shared__ unsigned short Bs[128 * BK];

    const int tid  = threadIdx.x;
    const int lane = tid & 63;
    const int wave = tid >> 6;
    const int rowBase = blockIdx.y * 128;
    const int colBase = blockIdx.x * 128;

    const int waveM = (wave >> 1) * 64;
    const int waveN = (wave & 1) * 64;

    f32x4 acc[4][4] = {};

    const int ldRow = lane >> 3;          // 0..7
    const int ldCol = (lane & 7) * 8;     // 8 elems/lane
    const int mrow  = lane & 15;
    const int kq    = (lane >> 4) * 8;

    for (int k0 = 0; k0 < KTOT; k0 += BK) {
#pragma unroll
        for (int it = 0; it < 4; ++it) {
            const int c = wave * 4 + it;                   // chunk 0..15
            const size_t aoff = (size_t)(rowBase + c * 8 + ldRow) * KTOT + k0 + ldCol;
            if (A_F32) {
                const float* ga = (const float*)Av + aoff;
                float4 f0 = *(const float4*)ga;
                float4 f1 = *(const float4*)(ga + 4);
                int4 p;
                p.x = (uint32_t)f2b(f0.x) | ((uint32_t)f2b(f0.y) << 16);
                p.y = (uint32_t)f2b(f0.z) | ((uint32_t)f2b(f0.w) << 16);
                p.z = (uint32_t)f2b(f1.x) | ((uint32_t)f2b(f1.y) << 16);
                p.w = (uint32_t)f2b(f1.z) | ((uint32_t)f2b(f1.w) << 16);
                *(int4*)&As[c * 512 + lane * 8] = p;
            } else {
                stage16((const unsigned short*)Av + aoff, &As[c * 512 + lane * 8]);
            }
            stage16(Bt + (size_t)(colBase + c * 8 + ldRow) * KTOT + k0 + ldCol,
                    &Bs[c * 512 + lane * 8]);
        }
        __syncthreads();

#pragma unroll
        for (int ks = 0; ks < 2; ++ks) {
            bf16x8 a_f[4], b_f[4];
#pragma unroll
            for (int i = 0; i < 4; ++i)
                a_f[i] = *(const bf16x8*)&As[(waveM + i * 16 + mrow) * BK + ks * 32 + kq];
#pragma unroll
            for (int j = 0; j < 4; ++j)
                b_f[j] = *(const bf16x8*)&Bs[(waveN + j * 16 + mrow) * BK + ks * 32 + kq];
#pragma unroll
            for (int i = 0; i < 4; ++i)
#pragma unroll
                for (int j = 0; j < 4; ++j)
                    acc[i][j] = __builtin_amdgcn_mfma_f32_16x16x32_bf16(
                        a_f[i], b_f[j], acc[i][j], 0, 0, 0);
        }
        __syncthreads();
    }

    // Epilogue: C/D layout col(n)=lane&15, row(m)=(lane>>4)*4+reg
    const int cRow = (lane >> 4) * 4;
    const int cCol = lane & 15;
#pragma unroll
    for (int i = 0; i < 4; ++i) {
#pragma unroll
        for (int j = 0; j < 4; ++j) {
            const int col = colBase + waveN + j * 16 + cCol;
            const float bv = bias[col];
#pragma unroll
            for (int r = 0; r < 4; ++r) {
                const int row = rowBase + waveM + i * 16 + cRow + r;
                float z = acc[i][j][r] + bv;
                if (DO_GELU)
                    z = 0.5f * z * (1.f + erff(z * 0.70710678118654752f));
                const size_t off = (size_t)row * Ncols + col;
                if (C_F32) ((float*)Cv)[off] = z;
                else       ((unsigned short*)Cv)[off] = f2b(z);
            }
        }
    }
}

// ---------------------------------------------------------------------------
extern "C" void kernel_launch(void* const* d_in, const int* in_sizes, int n_in,
                              void* d_out, int out_size, void* d_ws, size_t ws_size,
                              hipStream_t stream) {
    const float* x      = (const float*)d_in[0];   // [4096,1024] fp32
    const float* fc1_c0 = (const float*)d_in[1];
    const float* fc1_c1 = (const float*)d_in[2];
    const float* fc1_c2 = (const float*)d_in[3];
    const float* fc1_b  = (const float*)d_in[4];
    const float* fc2_c0 = (const float*)d_in[5];
    const float* fc2_c1 = (const float*)d_in[6];
    const float* fc2_c2 = (const float*)d_in[7];
    const float* fc2_b  = (const float*)d_in[8];

    // Workspace (42 MB peak):
    //   [0,8M)   W   bf16 — W1t [4096][1024], later W2t [1024][4096]
    //   [8,10M)  T   f32 scratch
    //   [10,42M) h   bf16 [4096][4096]
    char* ws = (char*)d_ws;
    unsigned short* W = (unsigned short*)(ws);
    float*          T = (float*)(ws + (8u << 20));
    unsigned short* h = (unsigned short*)(ws + (10u << 20));

    // ---- layer 1: in (8,16,8) -> out (16,16,16)
    build_T<8, 16><<<2048, 256, 0, stream>>>(fc1_c1, fc1_c2, T);
    // threads = M*K/N3 = 4096*1024/8 = 524288
    build_W<8, 16, 8, 16, 16, 16><<<2048, 256, 0, stream>>>(fc1_c0, T, W);
    // GEMM1: h = gelu(x @ W1^T + b1)   [4096 x 4096], K=1024, A fp32, C bf16
    gemm_bias_act<1024, true, true, false>
        <<<dim3(32, 32), 256, 0, stream>>>(x, W, fc1_b, h, 4096);

    // ---- layer 2: in (16,16,16) -> out (8,16,8)
    build_T<16, 8><<<2048, 256, 0, stream>>>(fc2_c1, fc2_c2, T);
    // threads = 1024*4096/16 = 262144
    build_W<16, 16, 16, 8, 16, 8><<<1024, 256, 0, stream>>>(fc2_c0, T, W);
    // GEMM2: out = h @ W2^T + b2       [4096 x 1024], K=4096, A bf16, C fp32
    gemm_bias_act<4096, false, false, true>
        <<<dim3(8, 32), 256, 0, stream>>>(h, W, fc2_b, d_out, 1024);
}

// Round 6
// 254.765 us; speedup vs baseline: 2.4934x; 1.0973x over previous
//
#include <hip/hip_runtime.h>
#include <stdint.h>

// ---------- bf16 helpers (storage = unsigned short) ----------
__device__ __forceinline__ float b2f(unsigned short u) {
    union { uint32_t i; float f; } v; v.i = ((uint32_t)u) << 16; return v.f;
}
__device__ __forceinline__ unsigned short f2b(float f) {
    union { float f; uint32_t i; } v; v.f = f;
    uint32_t r = v.i + 0x7fffu + ((v.i >> 16) & 1u);   // RNE
    return (unsigned short)(r >> 16);
}

typedef __bf16 bf16x8 __attribute__((ext_vector_type(8)));
typedef float  f32x4  __attribute__((ext_vector_type(4)));

// ---------- 16B/lane async stage: global -> LDS ----------
__device__ __forceinline__ void stage16(const unsigned short* g, unsigned short* l) {
    __builtin_amdgcn_global_load_lds(
        (const __attribute__((address_space(1))) void*)g,
        (__attribute__((address_space(3))) void*)l, 16, 0, 0);
}

// ---------------------------------------------------------------------------
// cvt: xb = bf16(x), 8 elems/thread, RNE. 4.19M elems -> 2048 blocks.
// ---------------------------------------------------------------------------
__global__ __launch_bounds__(256)
void cvt_f32_bf16(const float* __restrict__ x, unsigned short* __restrict__ xb) {
    int t = blockIdx.x * 256 + threadIdx.x;
    const float4* p = (const float4*)(x + (size_t)t * 8);
    float4 f0 = p[0], f1 = p[1];
    int4 o;
    o.x = (uint32_t)f2b(f0.x) | ((uint32_t)f2b(f0.y) << 16);
    o.y = (uint32_t)f2b(f0.z) | ((uint32_t)f2b(f0.w) << 16);
    o.z = (uint32_t)f2b(f1.x) | ((uint32_t)f2b(f1.y) << 16);
    o.w = (uint32_t)f2b(f1.z) | ((uint32_t)f2b(f1.w) << 16);
    ((int4*)xb)[t] = o;
}

// ---------------------------------------------------------------------------
// build_T: T[rm=(r1*16+n2)*16+m2][n3][m3] = sum_r2 c1[rm][r2]*c2[(r2*N3+n3)*M3+m3]
// ---------------------------------------------------------------------------
template<int N3, int M3>
__global__ void build_T(const float* __restrict__ c1,
                        const float* __restrict__ c2,
                        float* __restrict__ T) {
    int e = blockIdx.x * 256 + threadIdx.x;
    int m3 = e % M3;
    int t  = e / M3;
    int n3 = t % N3;
    int rm = t / N3;
    float s = 0.f;
#pragma unroll
    for (int r2 = 0; r2 < 16; ++r2)
        s += c1[rm * 16 + r2] * c2[(r2 * N3 + n3) * M3 + m3];
    T[e] = s;
}

// ---------------------------------------------------------------------------
// build_W (coalesced remap): thread t = (((n1*M1+m1)*N2+n2)*M2+m2)*M3+m3.
//   W idx = ((m1*M2+m2)*M3+m3)*K + (n1*N2+n2)*N3 + n3
//   T idx = (((r1*16+n2)*16+m2)*N3 + n3)*M3 + m3
// ---------------------------------------------------------------------------
template<int N1, int N2, int N3, int M1, int M2, int M3>
__global__ __launch_bounds__(256)
void build_W(const float* __restrict__ c0,
             const float* __restrict__ T,
             unsigned short* __restrict__ W) {
    constexpr int K = N1 * N2 * N3;
    int t  = blockIdx.x * 256 + threadIdx.x;
    int m3 = t % M3;
    int m2 = (t / M3) % M2;
    int n2 = (t / (M3 * M2)) % N2;
    int m1 = (t / (M3 * M2 * N2)) % M1;
    int n1 =  t / (M3 * M2 * N2 * M1);

    float c0r[16];
    const float4* c0p = (const float4*)(c0 + (n1 * M1 + m1) * 16);
#pragma unroll
    for (int i = 0; i < 4; ++i) ((float4*)c0r)[i] = c0p[i];

    float acc[N3] = {};
#pragma unroll
    for (int r1 = 0; r1 < 16; ++r1) {
        const float* Tp = T + (size_t)(((r1 * 16 + n2) * 16 + m2) * N3) * M3 + m3;
#pragma unroll
        for (int n3 = 0; n3 < N3; ++n3)
            acc[n3] += c0r[r1] * Tp[n3 * M3];
    }

    unsigned short ob[N3];
#pragma unroll
    for (int n3 = 0; n3 < N3; ++n3) ob[n3] = f2b(acc[n3]);

    unsigned short* dst = W + (size_t)((m1 * M2 + m2) * M3 + m3) * K
                            + (n1 * N2 + n2) * N3;
#pragma unroll
    for (int c = 0; c < N3 / 8; ++c)
        ((int4*)dst)[c] = ((const int4*)ob)[c];
}

// ---------------------------------------------------------------------------
// GEMM: C[M][N] = A[M][K] * Bt[N][K]^T + bias[N] (fp32), optional exact GELU.
// 128x128 tile, BK=64, 4 waves, 4x4 of 16x16x32 bf16 MFMA per wave.
// LDS layout XOR-swizzled: LDS[row][j] holds global k-chunk (j ^ (row&7)).
//   Staging permutes the GLOBAL address per lane (LDS dst stays lane*16,
//   as global_load_lds requires); reads use jswz = jglob ^ (row&7).
//   Result: each quarter-wave's b128 reads cover all 32 banks at 2-way (free).
// ---------------------------------------------------------------------------
template<int KTOT, bool DO_GELU, bool A_F32, bool C_F32>
__global__ __launch_bounds__(256)
void gemm_bias_act(const void* __restrict__ Av,
                   const unsigned short* __restrict__ Bt,
                   const float* __restrict__ bias,
                   void* __restrict__ Cv,
                   int Ncols) {
    constexpr int BK = 64;
    __shared__ unsigned short As[128 * BK];
    __shared__ unsigned short Bs[128 * BK];

    const int tid  = threadIdx.x;
    const int lane = tid & 63;
    const int wave = tid >> 6;
    const int rowBase = blockIdx.y * 128;
    const int colBase = blockIdx.x * 128;

    const int waveM = (wave >> 1) * 64;
    const int waveN = (wave & 1) * 64;

    f32x4 acc[4][4] = {};

    const int lr    = lane >> 3;          // local row within chunk, 0..7
    const int jj    = lane & 7;           // LDS store chunk (8 elems)
    const int jglob = jj ^ lr;            // fetched global chunk (swizzle)
    const int mrow  = lane & 15;
    const int kc    = lane >> 4;          // 0..3 (k-chunk within half-BK)
    const int rkey  = mrow & 7;           // read-side swizzle key

    for (int k0 = 0; k0 < KTOT; k0 += BK) {
#pragma unroll
        for (int it = 0; it < 4; ++it) {
            const int c = wave * 4 + it;                   // chunk 0..15
            const size_t aoff = (size_t)(rowBase + c * 8 + lr) * KTOT + k0 + jglob * 8;
            if (A_F32) {
                const float* ga = (const float*)Av + aoff;
                float4 f0 = *(const float4*)ga;
                float4 f1 = *(const float4*)(ga + 4);
                int4 p;
                p.x = (uint32_t)f2b(f0.x) | ((uint32_t)f2b(f0.y) << 16);
                p.y = (uint32_t)f2b(f0.z) | ((uint32_t)f2b(f0.w) << 16);
                p.z = (uint32_t)f2b(f1.x) | ((uint32_t)f2b(f1.y) << 16);
                p.w = (uint32_t)f2b(f1.z) | ((uint32_t)f2b(f1.w) << 16);
                *(int4*)&As[c * 512 + lane * 8] = p;
            } else {
                stage16((const unsigned short*)Av + aoff, &As[c * 512 + lane * 8]);
            }
            stage16(Bt + (size_t)(colBase + c * 8 + lr) * KTOT + k0 + jglob * 8,
                    &Bs[c * 512 + lane * 8]);
        }
        __syncthreads();

#pragma unroll
        for (int ks = 0; ks < 2; ++ks) {
            const int jswz = ((ks * 4 + kc) ^ rkey) * 8;
            bf16x8 a_f[4], b_f[4];
#pragma unroll
            for (int i = 0; i < 4; ++i)
                a_f[i] = *(const bf16x8*)&As[(waveM + i * 16 + mrow) * BK + jswz];
#pragma unroll
            for (int j = 0; j < 4; ++j)
                b_f[j] = *(const bf16x8*)&Bs[(waveN + j * 16 + mrow) * BK + jswz];
#pragma unroll
            for (int i = 0; i < 4; ++i)
#pragma unroll
                for (int j = 0; j < 4; ++j)
                    acc[i][j] = __builtin_amdgcn_mfma_f32_16x16x32_bf16(
                        a_f[i], b_f[j], acc[i][j], 0, 0, 0);
        }
        __syncthreads();
    }

    // Epilogue: C/D layout col(n)=lane&15, row(m)=(lane>>4)*4+reg
    const int cRow = (lane >> 4) * 4;
    const int cCol = lane & 15;
#pragma unroll
    for (int i = 0; i < 4; ++i) {
#pragma unroll
        for (int j = 0; j < 4; ++j) {
            const int col = colBase + waveN + j * 16 + cCol;
            const float bv = bias[col];
#pragma unroll
            for (int r = 0; r < 4; ++r) {
                const int row = rowBase + waveM + i * 16 + cRow + r;
                float z = acc[i][j][r] + bv;
                if (DO_GELU)
                    z = 0.5f * z * (1.f + erff(z * 0.70710678118654752f));
                const size_t off = (size_t)row * Ncols + col;
                if (C_F32) ((float*)Cv)[off] = z;
                else       ((unsigned short*)Cv)[off] = f2b(z);
            }
        }
    }
}

// ---------------------------------------------------------------------------
extern "C" void kernel_launch(void* const* d_in, const int* in_sizes, int n_in,
                              void* d_out, int out_size, void* d_ws, size_t ws_size,
                              hipStream_t stream) {
    const float* x      = (const float*)d_in[0];   // [4096,1024] fp32
    const float* fc1_c0 = (const float*)d_in[1];
    const float* fc1_c1 = (const float*)d_in[2];
    const float* fc1_c2 = (const float*)d_in[3];
    const float* fc1_b  = (const float*)d_in[4];
    const float* fc2_c0 = (const float*)d_in[5];
    const float* fc2_c1 = (const float*)d_in[6];
    const float* fc2_c2 = (const float*)d_in[7];
    const float* fc2_b  = (const float*)d_in[8];

    // Preferred workspace layout (50 MB):
    //   [0,8M)   W    bf16 — W1t [4096][1024], later W2t [1024][4096]
    //   [8,10M)  T    f32 scratch
    //   [10,18M) xb   bf16 copy of x [4096][1024]
    //   [18,50M) h    bf16 [4096][4096]
    // Fallback (<50 MB): no xb; GEMM1 repacks fp32 A in-kernel (42 MB peak).
    char* ws = (char*)d_ws;
    unsigned short* W  = (unsigned short*)(ws);
    float*          T  = (float*)(ws + (8u << 20));
    const bool big = ws_size >= (50ull << 20);
    unsigned short* xb = (unsigned short*)(ws + (10u << 20));
    unsigned short* h  = (unsigned short*)(ws + (big ? (18u << 20) : (10u << 20)));

    // ---- layer 1: in (8,16,8) -> out (16,16,16)
    build_T<8, 16><<<2048, 256, 0, stream>>>(fc1_c1, fc1_c2, T);
    build_W<8, 16, 8, 16, 16, 16><<<2048, 256, 0, stream>>>(fc1_c0, T, W);
    if (big) {
        cvt_f32_bf16<<<2048, 256, 0, stream>>>(x, xb);
        gemm_bias_act<1024, true, false, false>
            <<<dim3(32, 32), 256, 0, stream>>>(xb, W, fc1_b, h, 4096);
    } else {
        gemm_bias_act<1024, true, true, false>
            <<<dim3(32, 32), 256, 0, stream>>>(x, W, fc1_b, h, 4096);
    }

    // ---- layer 2: in (16,16,16) -> out (8,16,8)
    build_T<16, 8><<<2048, 256, 0, stream>>>(fc2_c1, fc2_c2, T);
    build_W<16, 16, 16, 8, 16, 8><<<1024, 256, 0, stream>>>(fc2_c0, T, W);
    gemm_bias_act<4096, false, false, true>
        <<<dim3(8, 32), 256, 0, stream>>>(h, W, fc2_b, d_out, 1024);
}

// Round 8
// 237.952 us; speedup vs baseline: 2.6696x; 1.0707x over previous
//
#include <hip/hip_runtime.h>
#include <stdint.h>

// ---------- bf16 helpers (storage = unsigned short) ----------
__device__ __forceinline__ float b2f(unsigned short u) {
    union { uint32_t i; float f; } v; v.i = ((uint32_t)u) << 16; return v.f;
}
__device__ __forceinline__ unsigned short f2b(float f) {
    union { float f; uint32_t i; } v; v.f = f;
    uint32_t r = v.i + 0x7fffu + ((v.i >> 16) & 1u);   // RNE
    return (unsigned short)(r >> 16);
}

typedef __bf16 bf16x8 __attribute__((ext_vector_type(8)));
typedef float  f32x4  __attribute__((ext_vector_type(4)));

// ---------- 16B/lane async stage: global -> LDS ----------
__device__ __forceinline__ void stage16(const unsigned short* g, unsigned short* l) {
    __builtin_amdgcn_global_load_lds(
        (const __attribute__((address_space(1))) void*)g,
        (__attribute__((address_space(3))) void*)l, 16, 0, 0);
}

// ---------------------------------------------------------------------------
// cvt: xb = bf16(x), 8 elems/thread.
// ---------------------------------------------------------------------------
__global__ __launch_bounds__(256)
void cvt_f32_bf16(const float* __restrict__ x, unsigned short* __restrict__ xb) {
    int t = blockIdx.x * 256 + threadIdx.x;
    const float4* p = (const float4*)(x + (size_t)t * 8);
    float4 f0 = p[0], f1 = p[1];
    int4 o;
    o.x = (uint32_t)f2b(f0.x) | ((uint32_t)f2b(f0.y) << 16);
    o.y = (uint32_t)f2b(f0.z) | ((uint32_t)f2b(f0.w) << 16);
    o.z = (uint32_t)f2b(f1.x) | ((uint32_t)f2b(f1.y) << 16);
    o.w = (uint32_t)f2b(f1.z) | ((uint32_t)f2b(f1.w) << 16);
    ((int4*)xb)[t] = o;
}

// ---------------------------------------------------------------------------
// build_T: T[rm=(r1*16+n2)*16+m2][n3][m3] = sum_r2 c1[rm][r2]*c2[(r2*N3+n3)*M3+m3]
// ---------------------------------------------------------------------------
template<int N3, int M3>
__global__ void build_T(const float* __restrict__ c1,
                        const float* __restrict__ c2,
                        float* __restrict__ T) {
    int e = blockIdx.x * 256 + threadIdx.x;
    int m3 = e % M3;
    int t  = e / M3;
    int n3 = t % N3;
    int rm = t / N3;
    float s = 0.f;
#pragma unroll
    for (int r2 = 0; r2 < 16; ++r2)
        s += c1[rm * 16 + r2] * c2[(r2 * N3 + n3) * M3 + m3];
    T[e] = s;
}

// ---------------------------------------------------------------------------
// build_W (coalesced remap): thread t = (((n1*M1+m1)*N2+n2)*M2+m2)*M3+m3.
// ---------------------------------------------------------------------------
template<int N1, int N2, int N3, int M1, int M2, int M3>
__global__ __launch_bounds__(256)
void build_W(const float* __restrict__ c0,
             const float* __restrict__ T,
             unsigned short* __restrict__ W) {
    constexpr int K = N1 * N2 * N3;
    int t  = blockIdx.x * 256 + threadIdx.x;
    int m3 = t % M3;
    int m2 = (t / M3) % M2;
    int n2 = (t / (M3 * M2)) % N2;
    int m1 = (t / (M3 * M2 * N2)) % M1;
    int n1 =  t / (M3 * M2 * N2 * M1);

    float c0r[16];
    const float4* c0p = (const float4*)(c0 + (n1 * M1 + m1) * 16);
#pragma unroll
    for (int i = 0; i < 4; ++i) ((float4*)c0r)[i] = c0p[i];

    float acc[N3] = {};
#pragma unroll
    for (int r1 = 0; r1 < 16; ++r1) {
        const float* Tp = T + (size_t)(((r1 * 16 + n2) * 16 + m2) * N3) * M3 + m3;
#pragma unroll
        for (int n3 = 0; n3 < N3; ++n3)
            acc[n3] += c0r[r1] * Tp[n3 * M3];
    }

    unsigned short ob[N3];
#pragma unroll
    for (int n3 = 0; n3 < N3; ++n3) ob[n3] = f2b(acc[n3]);

    unsigned short* dst = W + (size_t)((m1 * M2 + m2) * M3 + m3) * K
                            + (n1 * N2 + n2) * N3;
#pragma unroll
    for (int c = 0; c < N3 / 8; ++c)
        ((int4*)dst)[c] = ((const int4*)ob)[c];
}

// ---------------------------------------------------------------------------
// GEMM: C[M][N] = A[M][K] * Bt[N][K]^T + bias[N] (fp32), optional exact GELU.
// Tile BM x BN (BN=128), BK=64, 4 waves; wave tile (BM/2) x 64 via
// (BM/32) x 4 of 16x16x32 MFMA. XOR-swizzled LDS (conflict-free, R6-verified).
// USE_GLLD: global_load_lds staging (R6-proven at BM=128, 4 blocks/CU);
// else register-mediated int4 staging (R3/R5-proven).
// ---------------------------------------------------------------------------
template<int BM, int KTOT, bool DO_GELU, bool A_F32, bool C_F32, bool USE_GLLD>
__global__ __launch_bounds__(256)
void gemm_bias_act(const void* __restrict__ Av,
                   const unsigned short* __restrict__ Bt,
                   const float* __restrict__ bias,
                   void* __restrict__ Cv,
                   int Ncols) {
    constexpr int BK = 64;
    constexpr int FI = BM / 32;               // frag rows per wave (4 or 2)
    __shared__ unsigned short As[BM * BK];
    __shared__ unsigned short Bs[128 * BK];

    const int tid  = threadIdx.x;
    const int lane = tid & 63;
    const int wave = tid >> 6;
    const int rowBase = blockIdx.y * BM;
    const int colBase = blockIdx.x * 128;

    const int waveM = (wave >> 1) * (BM / 2);
    const int waveN = (wave & 1) * 64;

    f32x4 acc[FI][4] = {};

    const int lr    = lane >> 3;          // local row within 8-row chunk
    const int jj    = lane & 7;           // LDS store chunk
    const int jglob = jj ^ lr;            // swizzled global chunk
    const int mrow  = lane & 15;
    const int kc    = lane >> 4;          // 0..3
    const int rkey  = mrow & 7;

    for (int k0 = 0; k0 < KTOT; k0 += BK) {
        // ---- stage A: BM/8 chunks; BM/32 per wave
#pragma unroll
        for (int it = 0; it < BM / 32; ++it) {
            const int c = wave * (BM / 32) + it;
            const size_t aoff = (size_t)(rowBase + c * 8 + lr) * KTOT + k0 + jglob * 8;
            if (A_F32) {
                const float* ga = (const float*)Av + aoff;
                float4 f0 = *(const float4*)ga;
                float4 f1 = *(const float4*)(ga + 4);
                int4 p;
                p.x = (uint32_t)f2b(f0.x) | ((uint32_t)f2b(f0.y) << 16);
                p.y = (uint32_t)f2b(f0.z) | ((uint32_t)f2b(f0.w) << 16);
                p.z = (uint32_t)f2b(f1.x) | ((uint32_t)f2b(f1.y) << 16);
                p.w = (uint32_t)f2b(f1.z) | ((uint32_t)f2b(f1.w) << 16);
                *(int4*)&As[c * 512 + lane * 8] = p;
            } else if (USE_GLLD) {
                stage16((const unsigned short*)Av + aoff, &As[c * 512 + lane * 8]);
            } else {
                *(int4*)&As[c * 512 + lane * 8] =
                    *(const int4*)((const unsigned short*)Av + aoff);
            }
        }
        // ---- stage B: 16 chunks; 4 per wave
#pragma unroll
        for (int it = 0; it < 4; ++it) {
            const int c = wave * 4 + it;
            const unsigned short* gb =
                Bt + (size_t)(colBase + c * 8 + lr) * KTOT + k0 + jglob * 8;
            if (USE_GLLD) stage16(gb, &Bs[c * 512 + lane * 8]);
            else          *(int4*)&Bs[c * 512 + lane * 8] = *(const int4*)gb;
        }
        __syncthreads();

#pragma unroll
        for (int ks = 0; ks < 2; ++ks) {
            const int jswz = ((ks * 4 + kc) ^ rkey) * 8;
            bf16x8 a_f[FI], b_f[4];
#pragma unroll
            for (int i = 0; i < FI; ++i)
                a_f[i] = *(const bf16x8*)&As[(waveM + i * 16 + mrow) * BK + jswz];
#pragma unroll
            for (int j = 0; j < 4; ++j)
                b_f[j] = *(const bf16x8*)&Bs[(waveN + j * 16 + mrow) * BK + jswz];
#pragma unroll
            for (int i = 0; i < FI; ++i)
#pragma unroll
                for (int j = 0; j < 4; ++j)
                    acc[i][j] = __builtin_amdgcn_mfma_f32_16x16x32_bf16(
                        a_f[i], b_f[j], acc[i][j], 0, 0, 0);
        }
        __syncthreads();
    }

    // Epilogue: C/D layout col(n)=lane&15, row(m)=(lane>>4)*4+reg
    const int cRow = (lane >> 4) * 4;
    const int cCol = lane & 15;
#pragma unroll
    for (int i = 0; i < FI; ++i) {
#pragma unroll
        for (int j = 0; j < 4; ++j) {
            const int col = colBase + waveN + j * 16 + cCol;
            const float bv = bias[col];
#pragma unroll
            for (int r = 0; r < 4; ++r) {
                const int row = rowBase + waveM + i * 16 + cRow + r;
                float z = acc[i][j][r] + bv;
                if (DO_GELU)
                    z = 0.5f * z * (1.f + erff(z * 0.70710678118654752f));
                const size_t off = (size_t)row * Ncols + col;
                if (C_F32) ((float*)Cv)[off] = z;
                else       ((unsigned short*)Cv)[off] = f2b(z);
            }
        }
    }
}

// ---------------------------------------------------------------------------
extern "C" void kernel_launch(void* const* d_in, const int* in_sizes, int n_in,
                              void* d_out, int out_size, void* d_ws, size_t ws_size,
                              hipStream_t stream) {
    const float* x      = (const float*)d_in[0];   // [4096,1024] fp32
    const float* fc1_c0 = (const float*)d_in[1];
    const float* fc1_c1 = (const float*)d_in[2];
    const float* fc1_c2 = (const float*)d_in[3];
    const float* fc1_b  = (const float*)d_in[4];
    const float* fc2_c0 = (const float*)d_in[5];
    const float* fc2_c1 = (const float*)d_in[6];
    const float* fc2_c2 = (const float*)d_in[7];
    const float* fc2_b  = (const float*)d_in[8];

    // Workspace layout (50 MB preferred):
    //   [0,8M)   W    bf16 — W1t [4096][1024], later W2t [1024][4096]
    //   [8,10M)  T    f32 scratch
    //   [10,18M) xb   bf16 copy of x
    //   [18,50M) h    bf16 [4096][4096]
    // Fallback (<50 MB): no xb; GEMM1 repacks fp32 A in-kernel.
    char* ws = (char*)d_ws;
    unsigned short* W  = (unsigned short*)(ws);
    float*          T  = (float*)(ws + (8u << 20));
    const bool big = ws_size >= (50ull << 20);
    unsigned short* xb = (unsigned short*)(ws + (10u << 20));
    unsigned short* h  = (unsigned short*)(ws + (big ? (18u << 20) : (10u << 20)));

    // ---- layer 1: in (8,16,8) -> out (16,16,16)
    build_T<8, 16><<<2048, 256, 0, stream>>>(fc1_c1, fc1_c2, T);
    build_W<8, 16, 8, 16, 16, 16><<<2048, 256, 0, stream>>>(fc1_c0, T, W);
    if (big) {
        cvt_f32_bf16<<<2048, 256, 0, stream>>>(x, xb);
        // GEMM1 (R6-proven config): 128x128 tile, glld staging, grid 32x32
        gemm_bias_act<128, 1024, true, false, false, true>
            <<<dim3(32, 32), 256, 0, stream>>>(xb, W, fc1_b, h, 4096);
    } else {
        gemm_bias_act<128, 1024, true, true, false, true>
            <<<dim3(32, 32), 256, 0, stream>>>(x, W, fc1_b, h, 4096);
    }

    // ---- layer 2: in (16,16,16) -> out (8,16,8)
    build_T<16, 8><<<2048, 256, 0, stream>>>(fc2_c1, fc2_c2, T);
    build_W<16, 16, 16, 8, 16, 8><<<1024, 256, 0, stream>>>(fc2_c0, T, W);
    // GEMM2: 64x128 tile (512 blocks, 2/CU), REGISTER staging, grid 8x64
    gemm_bias_act<64, 4096, false, false, true, false>
        <<<dim3(8, 64), 256, 0, stream>>>(h, W, fc2_b, d_out, 1024);
}